// Round 22
// baseline (780.777 us; speedup 1.0000x reference)
//
#include <hip/hip_runtime.h>
#include <hip/hip_bf16.h>

// B=2, S=4096, D=768, H=12, d_head=64.
// convert x/W -> 128^2 m97 GEMM (BK=32, XCD-chunk-swizzled) writing Q/K/V
// fragment-order images -> flash attention: 1536 single-tile blocks (LPT,
// XCD-local), 4 waves stripe the tile's k-blocks 4-way, K via wave-private
// LDS buf, V direct-to-VGPR, fixed-max softmax, dumps reuse dead K-bufs,
// single-barrier combine. LDS 34KB -> 4 blocks/CU. -> 128^2 out GEMM.

#define D_MODEL 768
#define SEQ 4096
#define NB 2
#define NHEAD 12

typedef __attribute__((ext_vector_type(8))) short short8;
typedef __attribute__((ext_vector_type(4))) float floatx4;
typedef __attribute__((ext_vector_type(16))) float floatx16;

#define SM_C 0.18033688011112042f  /* 0.125 * log2(e) */

#if __has_builtin(__builtin_amdgcn_exp2f)
#define EXP2(x) __builtin_amdgcn_exp2f(x)
#else
#define EXP2(x) __expf((x) * 0.6931471805599453f)
#endif

__device__ inline short fb(float f) {
    union { __hip_bfloat16 h; short s; } cv;
    cv.h = __float2bfloat16(f);
    return cv.s;
}
__device__ inline unsigned pk2(float a, float b) {
    float2 f; f.x = a; f.y = b;
    union { __hip_bfloat162 h; unsigned u; } cv;
    cv.h = __float22bfloat162_rn(f);
    return cv.u;
}
__device__ inline void gload16(const void* g, void* l) {
    __builtin_amdgcn_global_load_lds(
        (const __attribute__((address_space(1))) unsigned int*)g,
        (__attribute__((address_space(3))) unsigned int*)l, 16, 0, 0);
}

// ---------------------------------------------------------------------------
__global__ __launch_bounds__(256) void convert_bf16(const float* __restrict__ src,
                                                    short* __restrict__ dst, size_t n) {
    size_t i = ((size_t)blockIdx.x * 256 + threadIdx.x) * 8;
    if (i >= n) return;
    float4 f0 = *(const float4*)(src + i);
    float4 f1 = *(const float4*)(src + i + 4);
    uint4 u = {pk2(f0.x, f0.y), pk2(f0.z, f0.w), pk2(f1.x, f1.y), pk2(f1.z, f1.w)};
    *(uint4*)(dst + i) = u;
}

// W[K][N] fp32 -> Wt[N][K] bf16, 32x32 tiles. block (32,8).
__global__ __launch_bounds__(256) void transpose_bf16(const float* __restrict__ W,
                                                      short* __restrict__ Wt,
                                                      int K, int N) {
    __shared__ short t[32][33];
    const int n0 = blockIdx.x * 32, k0 = blockIdx.y * 32;
    const int tx = threadIdx.x, ty = threadIdx.y;
#pragma unroll
    for (int j = 0; j < 4; ++j)
        t[ty + j * 8][tx] = fb(W[(size_t)(k0 + ty + j * 8) * N + n0 + tx]);
    __syncthreads();
#pragma unroll
    for (int j = 0; j < 4; ++j)
        Wt[(size_t)(n0 + ty + j * 8) * K + k0 + tx] = t[tx][ty + j * 8];
}

// ---------------------------------------------------------------------------
// QKV GEMM (m97 structure, BK=32, XCD-chunk swizzle). Fragment-order images.
// ---------------------------------------------------------------------------
__global__ __launch_bounds__(256) void gemm_qkv128(const short* __restrict__ A,
                                                   const short* __restrict__ Bt,
                                                   const float* __restrict__ bias,
                                                   short* __restrict__ qimg,
                                                   short* __restrict__ kimg,
                                                   short* __restrict__ vimg) {
    const int K = D_MODEL;
    __shared__ short As[128][32];
    __shared__ short Bs[128][32];
    const int tid = threadIdx.x, lane = tid & 63, w = tid >> 6;
    const int wr = w >> 1, wc = w & 1;
    const int lo = lane & 15, hi = lane >> 4;
    const int orig = (blockIdx.x & 7) * 144 + (blockIdx.x >> 3);
    const int m0 = (orig / 18) * 128, n0 = (orig % 18) * 128;
    const int lr = lane >> 2, lc = (lane & 3) * 8;

    floatx4 acc[4][4] = {};
    const short* Ag = A  + (size_t)(m0 + w * 16 + lr) * K + lc;
    const short* Bg = Bt + (size_t)(n0 + w * 16 + lr) * K + lc;

    for (int k0 = 0; k0 < K; k0 += 32) {
        __syncthreads();
        gload16(Ag + k0,                  &As[w * 16][0]);
        gload16(Ag + k0 + (size_t)64 * K, &As[64 + w * 16][0]);
        gload16(Bg + k0,                  &Bs[w * 16][0]);
        gload16(Bg + k0 + (size_t)64 * K, &Bs[64 + w * 16][0]);
        __syncthreads();
        short8 a[4], bf[4];
#pragma unroll
        for (int m = 0; m < 4; ++m) a[m] = *(const short8*)&As[wr * 64 + m * 16 + lo][hi * 8];
#pragma unroll
        for (int n = 0; n < 4; ++n) bf[n] = *(const short8*)&Bs[wc * 64 + n * 16 + lo][hi * 8];
#pragma unroll
        for (int m = 0; m < 4; ++m)
#pragma unroll
            for (int n = 0; n < 4; ++n)
                acc[m][n] = __builtin_amdgcn_mfma_f32_16x16x32_bf16(a[m], bf[n], acc[m][n], 0, 0, 0);
    }

#pragma unroll
    for (int m = 0; m < 4; ++m)
#pragma unroll
        for (int n = 0; n < 4; ++n) {
            int col  = n0 + wc * 64 + n * 16 + lo;
            int row0 = m0 + wr * 64 + m * 16 + hi * 4;
            float bv = bias[col];
            if (col < D_MODEL) {                    // Q (pre-scaled), per (b,h,tile)
                int hq = col >> 6, dh = col & 63;
                int kc = dh >> 4, dl = (dh >> 3) & 1, d7 = dh & 7;
#pragma unroll
                for (int r = 0; r < 4; ++r) {
                    int row = row0 + r;
                    int bb = row >> 12, s = row & 4095;
                    size_t off = (((((size_t)bb * NHEAD + hq) * 64 + (s >> 6)) * 8
                                  + ((s >> 5) & 1) * 4 + kc) * 512)
                               + ((s & 31) + dl * 32) * 8 + d7;
                    qimg[off] = fb((acc[m][n][r] + bv) * SM_C);
                }
            } else if (col < 2 * D_MODEL) {         // K fragment-order image
                int kc2 = col - D_MODEL;
                int hh = kc2 >> 6, dh = kc2 & 63;
                int kc = dh >> 4, dl = (dh >> 3) & 1, d7 = dh & 7;
#pragma unroll
                for (int r = 0; r < 4; ++r) {
                    int row = row0 + r;
                    int bb = row >> 12, s = row & 4095;
                    int kb = s >> 6, kr = s & 63;
                    size_t base = (((size_t)bb * NHEAD + hh) * 64 + kb) * 4096;
                    kimg[base + ((kr >> 5) * 4 + kc) * 512 + ((kr & 31) + dl * 32) * 8 + d7] =
                        fb(acc[m][n][r] + bv);
                }
            } else {                                // V fragment-order image
                int vcol = col - 2 * D_MODEL;
                int hh = vcol >> 6, dh = vcol & 63;
                int bb = row0 >> 12, s = row0 & 4095;
                int kb = s >> 6, kr = s & 63;
                size_t base = (((size_t)bb * NHEAD + hh) * 64 + kb) * 4096;
                size_t off = base + ((dh >> 5) * 4 + (kr >> 4)) * 512
                           + ((dh & 31) + ((kr >> 3) & 1) * 32) * 8 + (kr & 7);
                uint2 u = {pk2(acc[m][n][0] + bv, acc[m][n][1] + bv),
                           pk2(acc[m][n][2] + bv, acc[m][n][3] + bv)};
                *(uint2*)&vimg[off] = u;
            }
        }
}

// ---------------------------------------------------------------------------
__global__ __launch_bounds__(256) void gemm_out128(const short* __restrict__ A,
                                                   const short* __restrict__ Bt,
                                                   const float* __restrict__ bias,
                                                   float* __restrict__ C) {
    const int K = D_MODEL, N = D_MODEL;
    __shared__ short As[128][32];
    __shared__ short Bs[128][32];
    const int tid = threadIdx.x, lane = tid & 63, w = tid >> 6;
    const int wr = w >> 1, wc = w & 1;
    const int lo = lane & 15, hi = lane >> 4;
    const int orig = (blockIdx.x & 7) * 48 + (blockIdx.x >> 3);
    const int m0 = (orig / 6) * 128, n0 = (orig % 6) * 128;
    const int lr = lane >> 2, lc = (lane & 3) * 8;

    floatx4 acc[4][4] = {};
    const short* Ag = A  + (size_t)(m0 + w * 16 + lr) * K + lc;
    const short* Bg = Bt + (size_t)(n0 + w * 16 + lr) * K + lc;

    for (int k0 = 0; k0 < K; k0 += 32) {
        __syncthreads();
        gload16(Ag + k0,                  &As[w * 16][0]);
        gload16(Ag + k0 + (size_t)64 * K, &As[64 + w * 16][0]);
        gload16(Bg + k0,                  &Bs[w * 16][0]);
        gload16(Bg + k0 + (size_t)64 * K, &Bs[64 + w * 16][0]);
        __syncthreads();
        short8 a[4], bf[4];
#pragma unroll
        for (int m = 0; m < 4; ++m) a[m] = *(const short8*)&As[wr * 64 + m * 16 + lo][hi * 8];
#pragma unroll
        for (int n = 0; n < 4; ++n) bf[n] = *(const short8*)&Bs[wc * 64 + n * 16 + lo][hi * 8];
#pragma unroll
        for (int m = 0; m < 4; ++m)
#pragma unroll
            for (int n = 0; n < 4; ++n)
                acc[m][n] = __builtin_amdgcn_mfma_f32_16x16x32_bf16(a[m], bf[n], acc[m][n], 0, 0, 0);
    }

#pragma unroll
    for (int m = 0; m < 4; ++m)
#pragma unroll
        for (int n = 0; n < 4; ++n) {
            int col  = n0 + wc * 64 + n * 16 + lo;
            int row0 = m0 + wr * 64 + m * 16 + hi * 4;
            float bv = bias[col];
#pragma unroll
            for (int r = 0; r < 4; ++r)
                C[(size_t)(row0 + r) * N + col] = acc[m][n][r] + bv;
        }
}

// ---------------------------------------------------------------------------
// Flash attention (causal). 1536 single-tile blocks (tile = 63 - rank: LPT,
// XCD-local heads); 4 waves stripe k-blocks 4-way (wave w: w, w+4, ...).
// K via wave-private 8KB LDS buf (vmcnt(8) top wait), V direct to VGPR.
// Fixed-max softmax; end dumps reuse dead K bufs; single-barrier combine
// (wave w finalizes qh=w&1, dv=w>>1). LDS 34KB -> 4 blocks/CU.
// ---------------------------------------------------------------------------
__global__ __launch_bounds__(256, 4) void attn_k(const short* __restrict__ qimg,
                                                 const short* __restrict__ kimg,
                                                 const short* __restrict__ vimg,
                                                 short* __restrict__ y) {
    const int L = blockIdx.x;
    const int xcd = L & 7, slot = L >> 3;
    const int hg = slot >> 6, trank = slot & 63;
    const int t = 63 - trank;                  // tile, longest first (LPT)
    const int g = hg * 8 + xcd;
    const int b = g / NHEAD, h = g % NHEAD;
    const int tid = threadIdx.x, lane = tid & 63, w = tid >> 6;
    const int l31 = lane & 31, hh = lane >> 5;

    __shared__ alignas(16) short KL[4][4096];  // per-wave K buf; reused for dumps
    __shared__ float LS[4][2][64];             // lsum dumps [w][qh][lane]

    const short* kbase = kimg + ((size_t)b * NHEAD + h) * 64 * 4096;
    const short* vbase = vimg + ((size_t)b * NHEAD + h) * 64 * 4096 + lane * 8;
    const short* qt = qimg + (((size_t)b * NHEAD + h) * 64 + t) * 4096 + lane * 8;
    short* Kbuf = &KL[w][0];

    const int nit = (t >= w) ? ((t - w) >> 2) + 1 : 0;

    floatx16 Oa = {}, Ob = {}, Oc = {}, Od = {};  // [qh0dv0][qh0dv1][qh1dv0][qh1dv1]
    float ls0 = 0.0f, ls1 = 0.0f;
    short8 qf0[4], qf1[4], vf[8];

    if (nit > 0) {
#pragma unroll
        for (int kc = 0; kc < 4; ++kc) {
            qf0[kc] = *(const short8*)(qt + kc * 512);
            qf1[kc] = *(const short8*)(qt + (4 + kc) * 512);
        }
        // prologue: K(w) -> LDS (first: oldest in queue), V(w) -> regs
        const short* ks = kbase + (size_t)w * 4096 + lane * 8;
#pragma unroll
        for (int c = 0; c < 8; ++c) gload16(ks + c * 512, Kbuf + c * 512);
        const short* vs = vbase + (size_t)w * 4096;
#pragma unroll
        for (int i = 0; i < 8; ++i) vf[i] = *(const short8*)(vs + i * 512);
    }

    for (int it = 0; it < nit; ++it) {
        const int s = w + 4 * it;              // my k-block

        // counted wait: K(s) landed in Kbuf; V(s) stays in flight.
        asm volatile("s_waitcnt vmcnt(8)" ::: "memory");
        __builtin_amdgcn_sched_barrier(0);

        // ---- QK (both 32-key halves) from private K buffer
        floatx16 S00 = {}, S10 = {}, S01 = {}, S11 = {};   // S[qh][kb2]
        __builtin_amdgcn_s_setprio(1);
#pragma unroll
        for (int kc = 0; kc < 4; ++kc) {
            short8 kf = *(const short8*)&Kbuf[kc * 512 + lane * 8];
            S00 = __builtin_amdgcn_mfma_f32_32x32x16_bf16(kf, qf0[kc], S00, 0, 0, 0);
            S10 = __builtin_amdgcn_mfma_f32_32x32x16_bf16(kf, qf1[kc], S10, 0, 0, 0);
        }
#pragma unroll
        for (int kc = 0; kc < 4; ++kc) {
            short8 kf = *(const short8*)&Kbuf[(4 + kc) * 512 + lane * 8];
            S01 = __builtin_amdgcn_mfma_f32_32x32x16_bf16(kf, qf0[kc], S01, 0, 0, 0);
            S11 = __builtin_amdgcn_mfma_f32_32x32x16_bf16(kf, qf1[kc], S11, 0, 0, 0);
        }
        __builtin_amdgcn_s_setprio(0);
        __builtin_amdgcn_sched_barrier(0);

        // ---- issue K(s+4) into the (now fully consumed) private buffer
        if (it + 1 < nit) {
            const short* ks = kbase + (size_t)(s + 4) * 4096 + lane * 8;
#pragma unroll
            for (int c = 0; c < 8; ++c) gload16(ks + c * 512, Kbuf + c * 512);
        }
        __builtin_amdgcn_sched_barrier(0);

        // ---- mask (diagonal block only; lands on wave t&3, last iter)
        if (s == t) {
            const int qg0 = t * 64 + l31, qg1 = qg0 + 32;
#pragma unroll
            for (int kb2 = 0; kb2 < 2; ++kb2) {
                int kb_base = s * 64 + kb2 * 32 + 4 * hh;
#pragma unroll
                for (int r = 0; r < 16; ++r) {
                    int kgl = kb_base + (r & 3) + 8 * (r >> 2);
                    if (kb2 == 0) {
                        if (kgl > qg0) S00[r] = -1e30f;
                        if (kgl > qg1) S10[r] = -1e30f;
                    } else {
                        if (kgl > qg0) S01[r] = -1e30f;
                        if (kgl > qg1) S11[r] = -1e30f;
                    }
                }
            }
        }

        // ---- softmax + pack + PV, per (qh, kb2); compiler waits vf before PV
#pragma unroll
        for (int kb2 = 0; kb2 < 2; ++kb2) {
            // qh = 0
            {
                floatx16& S = kb2 ? S01 : S00;
                unsigned wA[4], wB[4];
#pragma unroll
                for (int g4 = 0; g4 < 4; ++g4) {
                    float p0 = EXP2(S[4 * g4 + 0]), p1 = EXP2(S[4 * g4 + 1]);
                    float p2 = EXP2(S[4 * g4 + 2]), p3 = EXP2(S[4 * g4 + 3]);
                    ls0 += (p0 + p1) + (p2 + p3);
                    wA[g4] = pk2(p0, p1);
                    wB[g4] = pk2(p2, p3);
                }
#pragma unroll
                for (int c16 = 0; c16 < 2; ++c16) {
                    unsigned xa = wA[2 * c16], ya = wA[2 * c16 + 1];
                    unsigned xb = wB[2 * c16], yb = wB[2 * c16 + 1];
                    asm("v_permlane32_swap_b32 %0, %1" : "+v"(xa), "+v"(ya));
                    asm("v_permlane32_swap_b32 %0, %1" : "+v"(xb), "+v"(yb));
                    union { unsigned u[4]; short8 s8; } pa;
                    pa.u[0] = xa; pa.u[1] = xb; pa.u[2] = ya; pa.u[3] = yb;
                    const int kcg = kb2 * 2 + c16;
                    __builtin_amdgcn_s_setprio(1);
                    Oa = __builtin_amdgcn_mfma_f32_32x32x16_bf16(pa.s8, vf[kcg],     Oa, 0, 0, 0);
                    Ob = __builtin_amdgcn_mfma_f32_32x32x16_bf16(pa.s8, vf[4 + kcg], Ob, 0, 0, 0);
                    __builtin_amdgcn_s_setprio(0);
                }
            }
            // qh = 1
            {
                floatx16& S = kb2 ? S11 : S10;
                unsigned wA[4], wB[4];
#pragma unroll
                for (int g4 = 0; g4 < 4; ++g4) {
                    float p0 = EXP2(S[4 * g4 + 0]), p1 = EXP2(S[4 * g4 + 1]);
                    float p2 = EXP2(S[4 * g4 + 2]), p3 = EXP2(S[4 * g4 + 3]);
                    ls1 += (p0 + p1) + (p2 + p3);
                    wA[g4] = pk2(p0, p1);
                    wB[g4] = pk2(p2, p3);
                }
#pragma unroll
                for (int c16 = 0; c16 < 2; ++c16) {
                    unsigned xa = wA[2 * c16], ya = wA[2 * c16 + 1];
                    unsigned xb = wB[2 * c16], yb = wB[2 * c16 + 1];
                    asm("v_permlane32_swap_b32 %0, %1" : "+v"(xa), "+v"(ya));
                    asm("v_permlane32_swap_b32 %0, %1" : "+v"(xb), "+v"(yb));
                    union { unsigned u[4]; short8 s8; } pa;
                    pa.u[0] = xa; pa.u[1] = xb; pa.u[2] = ya; pa.u[3] = yb;
                    const int kcg = kb2 * 2 + c16;
                    __builtin_amdgcn_s_setprio(1);
                    Oc = __builtin_amdgcn_mfma_f32_32x32x16_bf16(pa.s8, vf[kcg],     Oc, 0, 0, 0);
                    Od = __builtin_amdgcn_mfma_f32_32x32x16_bf16(pa.s8, vf[4 + kcg], Od, 0, 0, 0);
                    __builtin_amdgcn_s_setprio(0);
                }
            }
        }
        __builtin_amdgcn_sched_barrier(0);

        // ---- issue V(s+4)
        if (it + 1 < nit) {
            const short* vs = vbase + (size_t)(s + 4) * 4096;
#pragma unroll
            for (int i = 0; i < 8; ++i) vf[i] = *(const short8*)(vs + i * 512);
        }
        __builtin_amdgcn_sched_barrier(0);
    }

    // ---- dump partials into my (dead) K buffer; zero-work waves dump zeros
    {
        unsigned* hslot = (unsigned*)&KL[w][0];
#pragma unroll
        for (int rp = 0; rp < 8; ++rp) {
            hslot[(0 * 8 + rp) * 64 + lane] = pk2(Oa[2 * rp], Oa[2 * rp + 1]);
            hslot[(1 * 8 + rp) * 64 + lane] = pk2(Ob[2 * rp], Ob[2 * rp + 1]);
            hslot[(2 * 8 + rp) * 64 + lane] = pk2(Oc[2 * rp], Oc[2 * rp + 1]);
            hslot[(3 * 8 + rp) * 64 + lane] = pk2(Od[2 * rp], Od[2 * rp + 1]);
        }
        LS[w][0][lane] = ls0;
        LS[w][1][lane] = ls1;
    }
    __syncthreads();

    // ---- combine: wave w finalizes (qh = w&1, dv = w>>1)
    {
        const int fqh = w & 1, dv = w >> 1;
        float lt = 0.0f;
#pragma unroll
        for (int ww = 0; ww < 4; ++ww)
            lt += LS[ww][fqh][l31] + LS[ww][fqh][l31 + 32];
        float inv = 1.0f / lt;

#pragma unroll
        for (int rp = 0; rp < 8; ++rp) {
            float o0 = 0.0f, o1 = 0.0f;
#pragma unroll
            for (int ww = 0; ww < 4; ++ww) {
                unsigned u = ((const unsigned*)&KL[ww][0])[((fqh * 2 + dv) * 8 + rp) * 64 + lane];
                o0 += __builtin_bit_cast(float, u << 16);
                o1 += __builtin_bit_cast(float, u & 0xffff0000u);
            }
            int r0 = 2 * rp, r1 = 2 * rp + 1;
            int q0r = (r0 & 3) + 8 * (r0 >> 2) + 4 * hh;
            int q1r = (r1 & 3) + 8 * (r1 >> 2) + 4 * hh;
            float iv0 = __shfl(inv, q0r, 64);
            float iv1 = __shfl(inv, q1r, 64);
            size_t rowb = ((size_t)b * SEQ + t * 64 + fqh * 32);
            y[(rowb + q0r) * D_MODEL + h * 64 + dv * 32 + l31] = fb(o0 * iv0);
            y[(rowb + q1r) * D_MODEL + h * 64 + dv * 32 + l31] = fb(o1 * iv1);
        }
    }
}

extern "C" void kernel_launch(void* const* d_in, const int* in_sizes, int n_in,
                              void* d_out, int out_size, void* d_ws, size_t ws_size,
                              hipStream_t stream) {
    (void)in_sizes; (void)n_in; (void)out_size; (void)ws_size;
    const float* x     = (const float*)d_in[0];
    const float* W_in  = (const float*)d_in[1];
    const float* b_in  = (const float*)d_in[2];
    const float* W_out = (const float*)d_in[3];
    const float* b_out = (const float*)d_in[4];
    float* out = (float*)d_out;

    const int M = NB * SEQ;  // 8192
    char* p = (char*)d_ws;
    short* xbf   = (short*)p; p += (size_t)M * D_MODEL * 2;
    short* wtin  = (short*)p; p += (size_t)3 * D_MODEL * D_MODEL * 2;
    short* wtout = (short*)p; p += (size_t)D_MODEL * D_MODEL * 2;
    short* qimg  = (short*)p; p += (size_t)M * D_MODEL * 2;
    short* kimg  = (short*)p; p += (size_t)NB * NHEAD * 64 * 4096 * 2;
    short* vimg  = (short*)p; p += (size_t)NB * NHEAD * 64 * 4096 * 2;
    short* yw    = (short*)p;

    convert_bf16<<<dim3((unsigned)((size_t)M * D_MODEL / 8 / 256)), 256, 0, stream>>>(
        x, xbf, (size_t)M * D_MODEL);
    transpose_bf16<<<dim3(3 * D_MODEL / 32, D_MODEL / 32), dim3(32, 8), 0, stream>>>(
        W_in, wtin, D_MODEL, 3 * D_MODEL);
    transpose_bf16<<<dim3(D_MODEL / 32, D_MODEL / 32), dim3(32, 8), 0, stream>>>(
        W_out, wtout, D_MODEL, D_MODEL);
    gemm_qkv128<<<dim3(1152), 256, 0, stream>>>(xbf, wtin, b_in, qimg, kimg, vimg);
    attn_k<<<dim3(NB * NHEAD * 64), 256, 0, stream>>>(qimg, kimg, vimg, yw);
    gemm_out128<<<dim3(384), 256, 0, stream>>>(yw, wtout, b_out, out);
}

// Round 23
// 168.695 us; speedup vs baseline: 4.6283x; 4.6283x over previous
//
#include <hip/hip_runtime.h>
#include <hip/hip_bf16.h>

// B=2, S=4096, D=768, H=12, d_head=64.
// convert x/W -> 128^2 m97 GEMM (BK=32, XCD-chunk-swizzled) writing Q/K/V
// fragment-order images -> flash attention: 1536 single-tile blocks (LPT,
// XCD-local), 4 waves stripe the tile's k-blocks 4-way, K via wave-private
// LDS buf, V direct-to-VGPR, fixed-max softmax, dumps reuse dead K-bufs,
// single-barrier combine. LDS 34KB + VGPR 124 -> 4 blocks/CU.
// launch_bounds(256,2): floor only -- the ",4" bound forced spill (R22).
// -> 128^2 out GEMM.

#define D_MODEL 768
#define SEQ 4096
#define NB 2
#define NHEAD 12

typedef __attribute__((ext_vector_type(8))) short short8;
typedef __attribute__((ext_vector_type(4))) float floatx4;
typedef __attribute__((ext_vector_type(16))) float floatx16;

#define SM_C 0.18033688011112042f  /* 0.125 * log2(e) */

#if __has_builtin(__builtin_amdgcn_exp2f)
#define EXP2(x) __builtin_amdgcn_exp2f(x)
#else
#define EXP2(x) __expf((x) * 0.6931471805599453f)
#endif

__device__ inline short fb(float f) {
    union { __hip_bfloat16 h; short s; } cv;
    cv.h = __float2bfloat16(f);
    return cv.s;
}
__device__ inline unsigned pk2(float a, float b) {
    float2 f; f.x = a; f.y = b;
    union { __hip_bfloat162 h; unsigned u; } cv;
    cv.h = __float22bfloat162_rn(f);
    return cv.u;
}
__device__ inline void gload16(const void* g, void* l) {
    __builtin_amdgcn_global_load_lds(
        (const __attribute__((address_space(1))) unsigned int*)g,
        (__attribute__((address_space(3))) unsigned int*)l, 16, 0, 0);
}

// ---------------------------------------------------------------------------
__global__ __launch_bounds__(256) void convert_bf16(const float* __restrict__ src,
                                                    short* __restrict__ dst, size_t n) {
    size_t i = ((size_t)blockIdx.x * 256 + threadIdx.x) * 8;
    if (i >= n) return;
    float4 f0 = *(const float4*)(src + i);
    float4 f1 = *(const float4*)(src + i + 4);
    uint4 u = {pk2(f0.x, f0.y), pk2(f0.z, f0.w), pk2(f1.x, f1.y), pk2(f1.z, f1.w)};
    *(uint4*)(dst + i) = u;
}

// W[K][N] fp32 -> Wt[N][K] bf16, 32x32 tiles. block (32,8).
__global__ __launch_bounds__(256) void transpose_bf16(const float* __restrict__ W,
                                                      short* __restrict__ Wt,
                                                      int K, int N) {
    __shared__ short t[32][33];
    const int n0 = blockIdx.x * 32, k0 = blockIdx.y * 32;
    const int tx = threadIdx.x, ty = threadIdx.y;
#pragma unroll
    for (int j = 0; j < 4; ++j)
        t[ty + j * 8][tx] = fb(W[(size_t)(k0 + ty + j * 8) * N + n0 + tx]);
    __syncthreads();
#pragma unroll
    for (int j = 0; j < 4; ++j)
        Wt[(size_t)(n0 + ty + j * 8) * K + k0 + tx] = t[tx][ty + j * 8];
}

// ---------------------------------------------------------------------------
// QKV GEMM (m97 structure, BK=32, XCD-chunk swizzle). Fragment-order images.
// ---------------------------------------------------------------------------
__global__ __launch_bounds__(256) void gemm_qkv128(const short* __restrict__ A,
                                                   const short* __restrict__ Bt,
                                                   const float* __restrict__ bias,
                                                   short* __restrict__ qimg,
                                                   short* __restrict__ kimg,
                                                   short* __restrict__ vimg) {
    const int K = D_MODEL;
    __shared__ short As[128][32];
    __shared__ short Bs[128][32];
    const int tid = threadIdx.x, lane = tid & 63, w = tid >> 6;
    const int wr = w >> 1, wc = w & 1;
    const int lo = lane & 15, hi = lane >> 4;
    const int orig = (blockIdx.x & 7) * 144 + (blockIdx.x >> 3);
    const int m0 = (orig / 18) * 128, n0 = (orig % 18) * 128;
    const int lr = lane >> 2, lc = (lane & 3) * 8;

    floatx4 acc[4][4] = {};
    const short* Ag = A  + (size_t)(m0 + w * 16 + lr) * K + lc;
    const short* Bg = Bt + (size_t)(n0 + w * 16 + lr) * K + lc;

    for (int k0 = 0; k0 < K; k0 += 32) {
        __syncthreads();
        gload16(Ag + k0,                  &As[w * 16][0]);
        gload16(Ag + k0 + (size_t)64 * K, &As[64 + w * 16][0]);
        gload16(Bg + k0,                  &Bs[w * 16][0]);
        gload16(Bg + k0 + (size_t)64 * K, &Bs[64 + w * 16][0]);
        __syncthreads();
        short8 a[4], bf[4];
#pragma unroll
        for (int m = 0; m < 4; ++m) a[m] = *(const short8*)&As[wr * 64 + m * 16 + lo][hi * 8];
#pragma unroll
        for (int n = 0; n < 4; ++n) bf[n] = *(const short8*)&Bs[wc * 64 + n * 16 + lo][hi * 8];
#pragma unroll
        for (int m = 0; m < 4; ++m)
#pragma unroll
            for (int n = 0; n < 4; ++n)
                acc[m][n] = __builtin_amdgcn_mfma_f32_16x16x32_bf16(a[m], bf[n], acc[m][n], 0, 0, 0);
    }

#pragma unroll
    for (int m = 0; m < 4; ++m)
#pragma unroll
        for (int n = 0; n < 4; ++n) {
            int col  = n0 + wc * 64 + n * 16 + lo;
            int row0 = m0 + wr * 64 + m * 16 + hi * 4;
            float bv = bias[col];
            if (col < D_MODEL) {                    // Q (pre-scaled), per (b,h,tile)
                int hq = col >> 6, dh = col & 63;
                int kc = dh >> 4, dl = (dh >> 3) & 1, d7 = dh & 7;
#pragma unroll
                for (int r = 0; r < 4; ++r) {
                    int row = row0 + r;
                    int bb = row >> 12, s = row & 4095;
                    size_t off = (((((size_t)bb * NHEAD + hq) * 64 + (s >> 6)) * 8
                                  + ((s >> 5) & 1) * 4 + kc) * 512)
                               + ((s & 31) + dl * 32) * 8 + d7;
                    qimg[off] = fb((acc[m][n][r] + bv) * SM_C);
                }
            } else if (col < 2 * D_MODEL) {         // K fragment-order image
                int kc2 = col - D_MODEL;
                int hh = kc2 >> 6, dh = kc2 & 63;
                int kc = dh >> 4, dl = (dh >> 3) & 1, d7 = dh & 7;
#pragma unroll
                for (int r = 0; r < 4; ++r) {
                    int row = row0 + r;
                    int bb = row >> 12, s = row & 4095;
                    int kb = s >> 6, kr = s & 63;
                    size_t base = (((size_t)bb * NHEAD + hh) * 64 + kb) * 4096;
                    kimg[base + ((kr >> 5) * 4 + kc) * 512 + ((kr & 31) + dl * 32) * 8 + d7] =
                        fb(acc[m][n][r] + bv);
                }
            } else {                                // V fragment-order image
                int vcol = col - 2 * D_MODEL;
                int hh = vcol >> 6, dh = vcol & 63;
                int bb = row0 >> 12, s = row0 & 4095;
                int kb = s >> 6, kr = s & 63;
                size_t base = (((size_t)bb * NHEAD + hh) * 64 + kb) * 4096;
                size_t off = base + ((dh >> 5) * 4 + (kr >> 4)) * 512
                           + ((dh & 31) + ((kr >> 3) & 1) * 32) * 8 + (kr & 7);
                uint2 u = {pk2(acc[m][n][0] + bv, acc[m][n][1] + bv),
                           pk2(acc[m][n][2] + bv, acc[m][n][3] + bv)};
                *(uint2*)&vimg[off] = u;
            }
        }
}

// ---------------------------------------------------------------------------
__global__ __launch_bounds__(256) void gemm_out128(const short* __restrict__ A,
                                                   const short* __restrict__ Bt,
                                                   const float* __restrict__ bias,
                                                   float* __restrict__ C) {
    const int K = D_MODEL, N = D_MODEL;
    __shared__ short As[128][32];
    __shared__ short Bs[128][32];
    const int tid = threadIdx.x, lane = tid & 63, w = tid >> 6;
    const int wr = w >> 1, wc = w & 1;
    const int lo = lane & 15, hi = lane >> 4;
    const int orig = (blockIdx.x & 7) * 48 + (blockIdx.x >> 3);
    const int m0 = (orig / 6) * 128, n0 = (orig % 6) * 128;
    const int lr = lane >> 2, lc = (lane & 3) * 8;

    floatx4 acc[4][4] = {};
    const short* Ag = A  + (size_t)(m0 + w * 16 + lr) * K + lc;
    const short* Bg = Bt + (size_t)(n0 + w * 16 + lr) * K + lc;

    for (int k0 = 0; k0 < K; k0 += 32) {
        __syncthreads();
        gload16(Ag + k0,                  &As[w * 16][0]);
        gload16(Ag + k0 + (size_t)64 * K, &As[64 + w * 16][0]);
        gload16(Bg + k0,                  &Bs[w * 16][0]);
        gload16(Bg + k0 + (size_t)64 * K, &Bs[64 + w * 16][0]);
        __syncthreads();
        short8 a[4], bf[4];
#pragma unroll
        for (int m = 0; m < 4; ++m) a[m] = *(const short8*)&As[wr * 64 + m * 16 + lo][hi * 8];
#pragma unroll
        for (int n = 0; n < 4; ++n) bf[n] = *(const short8*)&Bs[wc * 64 + n * 16 + lo][hi * 8];
#pragma unroll
        for (int m = 0; m < 4; ++m)
#pragma unroll
            for (int n = 0; n < 4; ++n)
                acc[m][n] = __builtin_amdgcn_mfma_f32_16x16x32_bf16(a[m], bf[n], acc[m][n], 0, 0, 0);
    }

#pragma unroll
    for (int m = 0; m < 4; ++m)
#pragma unroll
        for (int n = 0; n < 4; ++n) {
            int col  = n0 + wc * 64 + n * 16 + lo;
            int row0 = m0 + wr * 64 + m * 16 + hi * 4;
            float bv = bias[col];
#pragma unroll
            for (int r = 0; r < 4; ++r)
                C[(size_t)(row0 + r) * N + col] = acc[m][n][r] + bv;
        }
}

// ---------------------------------------------------------------------------
// Flash attention (causal). 1536 single-tile blocks (tile = 63 - rank: LPT,
// XCD-local heads); 4 waves stripe k-blocks 4-way (wave w: w, w+4, ...).
// K via wave-private 8KB LDS buf (vmcnt(8) top wait), V direct to VGPR.
// Fixed-max softmax; end dumps reuse dead K bufs; single-barrier combine
// (wave w finalizes qh=w&1, dv=w>>1). LDS 34KB + ~124 VGPR -> 4 blocks/CU.
// ---------------------------------------------------------------------------
__global__ __launch_bounds__(256, 2) void attn_k(const short* __restrict__ qimg,
                                                 const short* __restrict__ kimg,
                                                 const short* __restrict__ vimg,
                                                 short* __restrict__ y) {
    const int L = blockIdx.x;
    const int xcd = L & 7, slot = L >> 3;
    const int hg = slot >> 6, trank = slot & 63;
    const int t = 63 - trank;                  // tile, longest first (LPT)
    const int g = hg * 8 + xcd;
    const int b = g / NHEAD, h = g % NHEAD;
    const int tid = threadIdx.x, lane = tid & 63, w = tid >> 6;
    const int l31 = lane & 31, hh = lane >> 5;

    __shared__ alignas(16) short KL[4][4096];  // per-wave K buf; reused for dumps
    __shared__ float LS[4][2][64];             // lsum dumps [w][qh][lane]

    const short* kbase = kimg + ((size_t)b * NHEAD + h) * 64 * 4096;
    const short* vbase = vimg + ((size_t)b * NHEAD + h) * 64 * 4096 + lane * 8;
    const short* qt = qimg + (((size_t)b * NHEAD + h) * 64 + t) * 4096 + lane * 8;
    short* Kbuf = &KL[w][0];

    const int nit = (t >= w) ? ((t - w) >> 2) + 1 : 0;

    floatx16 Oa = {}, Ob = {}, Oc = {}, Od = {};  // [qh0dv0][qh0dv1][qh1dv0][qh1dv1]
    float ls0 = 0.0f, ls1 = 0.0f;
    short8 qf0[4], qf1[4], vf[8];

    if (nit > 0) {
#pragma unroll
        for (int kc = 0; kc < 4; ++kc) {
            qf0[kc] = *(const short8*)(qt + kc * 512);
            qf1[kc] = *(const short8*)(qt + (4 + kc) * 512);
        }
        // prologue: K(w) -> LDS (first: oldest in queue), V(w) -> regs
        const short* ks = kbase + (size_t)w * 4096 + lane * 8;
#pragma unroll
        for (int c = 0; c < 8; ++c) gload16(ks + c * 512, Kbuf + c * 512);
        const short* vs = vbase + (size_t)w * 4096;
#pragma unroll
        for (int i = 0; i < 8; ++i) vf[i] = *(const short8*)(vs + i * 512);
    }

    for (int it = 0; it < nit; ++it) {
        const int s = w + 4 * it;              // my k-block

        // counted wait: K(s) landed in Kbuf; V(s) stays in flight.
        asm volatile("s_waitcnt vmcnt(8)" ::: "memory");
        __builtin_amdgcn_sched_barrier(0);

        // ---- QK (both 32-key halves) from private K buffer
        floatx16 S00 = {}, S10 = {}, S01 = {}, S11 = {};   // S[qh][kb2]
        __builtin_amdgcn_s_setprio(1);
#pragma unroll
        for (int kc = 0; kc < 4; ++kc) {
            short8 kf = *(const short8*)&Kbuf[kc * 512 + lane * 8];
            S00 = __builtin_amdgcn_mfma_f32_32x32x16_bf16(kf, qf0[kc], S00, 0, 0, 0);
            S10 = __builtin_amdgcn_mfma_f32_32x32x16_bf16(kf, qf1[kc], S10, 0, 0, 0);
        }
#pragma unroll
        for (int kc = 0; kc < 4; ++kc) {
            short8 kf = *(const short8*)&Kbuf[(4 + kc) * 512 + lane * 8];
            S01 = __builtin_amdgcn_mfma_f32_32x32x16_bf16(kf, qf0[kc], S01, 0, 0, 0);
            S11 = __builtin_amdgcn_mfma_f32_32x32x16_bf16(kf, qf1[kc], S11, 0, 0, 0);
        }
        __builtin_amdgcn_s_setprio(0);
        __builtin_amdgcn_sched_barrier(0);

        // ---- issue K(s+4) into the (now fully consumed) private buffer
        if (it + 1 < nit) {
            const short* ks = kbase + (size_t)(s + 4) * 4096 + lane * 8;
#pragma unroll
            for (int c = 0; c < 8; ++c) gload16(ks + c * 512, Kbuf + c * 512);
        }
        __builtin_amdgcn_sched_barrier(0);

        // ---- mask (diagonal block only; lands on wave t&3, last iter)
        if (s == t) {
            const int qg0 = t * 64 + l31, qg1 = qg0 + 32;
#pragma unroll
            for (int kb2 = 0; kb2 < 2; ++kb2) {
                int kb_base = s * 64 + kb2 * 32 + 4 * hh;
#pragma unroll
                for (int r = 0; r < 16; ++r) {
                    int kgl = kb_base + (r & 3) + 8 * (r >> 2);
                    if (kb2 == 0) {
                        if (kgl > qg0) S00[r] = -1e30f;
                        if (kgl > qg1) S10[r] = -1e30f;
                    } else {
                        if (kgl > qg0) S01[r] = -1e30f;
                        if (kgl > qg1) S11[r] = -1e30f;
                    }
                }
            }
        }

        // ---- softmax + pack + PV, per (qh, kb2); compiler waits vf before PV
#pragma unroll
        for (int kb2 = 0; kb2 < 2; ++kb2) {
            // qh = 0
            {
                floatx16& S = kb2 ? S01 : S00;
                unsigned wA[4], wB[4];
#pragma unroll
                for (int g4 = 0; g4 < 4; ++g4) {
                    float p0 = EXP2(S[4 * g4 + 0]), p1 = EXP2(S[4 * g4 + 1]);
                    float p2 = EXP2(S[4 * g4 + 2]), p3 = EXP2(S[4 * g4 + 3]);
                    ls0 += (p0 + p1) + (p2 + p3);
                    wA[g4] = pk2(p0, p1);
                    wB[g4] = pk2(p2, p3);
                }
#pragma unroll
                for (int c16 = 0; c16 < 2; ++c16) {
                    unsigned xa = wA[2 * c16], ya = wA[2 * c16 + 1];
                    unsigned xb = wB[2 * c16], yb = wB[2 * c16 + 1];
                    asm("v_permlane32_swap_b32 %0, %1" : "+v"(xa), "+v"(ya));
                    asm("v_permlane32_swap_b32 %0, %1" : "+v"(xb), "+v"(yb));
                    union { unsigned u[4]; short8 s8; } pa;
                    pa.u[0] = xa; pa.u[1] = xb; pa.u[2] = ya; pa.u[3] = yb;
                    const int kcg = kb2 * 2 + c16;
                    __builtin_amdgcn_s_setprio(1);
                    Oa = __builtin_amdgcn_mfma_f32_32x32x16_bf16(pa.s8, vf[kcg],     Oa, 0, 0, 0);
                    Ob = __builtin_amdgcn_mfma_f32_32x32x16_bf16(pa.s8, vf[4 + kcg], Ob, 0, 0, 0);
                    __builtin_amdgcn_s_setprio(0);
                }
            }
            // qh = 1
            {
                floatx16& S = kb2 ? S11 : S10;
                unsigned wA[4], wB[4];
#pragma unroll
                for (int g4 = 0; g4 < 4; ++g4) {
                    float p0 = EXP2(S[4 * g4 + 0]), p1 = EXP2(S[4 * g4 + 1]);
                    float p2 = EXP2(S[4 * g4 + 2]), p3 = EXP2(S[4 * g4 + 3]);
                    ls1 += (p0 + p1) + (p2 + p3);
                    wA[g4] = pk2(p0, p1);
                    wB[g4] = pk2(p2, p3);
                }
#pragma unroll
                for (int c16 = 0; c16 < 2; ++c16) {
                    unsigned xa = wA[2 * c16], ya = wA[2 * c16 + 1];
                    unsigned xb = wB[2 * c16], yb = wB[2 * c16 + 1];
                    asm("v_permlane32_swap_b32 %0, %1" : "+v"(xa), "+v"(ya));
                    asm("v_permlane32_swap_b32 %0, %1" : "+v"(xb), "+v"(yb));
                    union { unsigned u[4]; short8 s8; } pa;
                    pa.u[0] = xa; pa.u[1] = xb; pa.u[2] = ya; pa.u[3] = yb;
                    const int kcg = kb2 * 2 + c16;
                    __builtin_amdgcn_s_setprio(1);
                    Oc = __builtin_amdgcn_mfma_f32_32x32x16_bf16(pa.s8, vf[kcg],     Oc, 0, 0, 0);
                    Od = __builtin_amdgcn_mfma_f32_32x32x16_bf16(pa.s8, vf[4 + kcg], Od, 0, 0, 0);
                    __builtin_amdgcn_s_setprio(0);
                }
            }
        }
        __builtin_amdgcn_sched_barrier(0);

        // ---- issue V(s+4)
        if (it + 1 < nit) {
            const short* vs = vbase + (size_t)(s + 4) * 4096;
#pragma unroll
            for (int i = 0; i < 8; ++i) vf[i] = *(const short8*)(vs + i * 512);
        }
        __builtin_amdgcn_sched_barrier(0);
    }

    // ---- dump partials into my (dead) K buffer; zero-work waves dump zeros
    {
        unsigned* hslot = (unsigned*)&KL[w][0];
#pragma unroll
        for (int rp = 0; rp < 8; ++rp) {
            hslot[(0 * 8 + rp) * 64 + lane] = pk2(Oa[2 * rp], Oa[2 * rp + 1]);
            hslot[(1 * 8 + rp) * 64 + lane] = pk2(Ob[2 * rp], Ob[2 * rp + 1]);
            hslot[(2 * 8 + rp) * 64 + lane] = pk2(Oc[2 * rp], Oc[2 * rp + 1]);
            hslot[(3 * 8 + rp) * 64 + lane] = pk2(Od[2 * rp], Od[2 * rp + 1]);
        }
        LS[w][0][lane] = ls0;
        LS[w][1][lane] = ls1;
    }
    __syncthreads();

    // ---- combine: wave w finalizes (qh = w&1, dv = w>>1)
    {
        const int fqh = w & 1, dv = w >> 1;
        float lt = 0.0f;
#pragma unroll
        for (int ww = 0; ww < 4; ++ww)
            lt += LS[ww][fqh][l31] + LS[ww][fqh][l31 + 32];
        float inv = 1.0f / lt;

#pragma unroll
        for (int rp = 0; rp < 8; ++rp) {
            float o0 = 0.0f, o1 = 0.0f;
#pragma unroll
            for (int ww = 0; ww < 4; ++ww) {
                unsigned u = ((const unsigned*)&KL[ww][0])[((fqh * 2 + dv) * 8 + rp) * 64 + lane];
                o0 += __builtin_bit_cast(float, u << 16);
                o1 += __builtin_bit_cast(float, u & 0xffff0000u);
            }
            int r0 = 2 * rp, r1 = 2 * rp + 1;
            int q0r = (r0 & 3) + 8 * (r0 >> 2) + 4 * hh;
            int q1r = (r1 & 3) + 8 * (r1 >> 2) + 4 * hh;
            float iv0 = __shfl(inv, q0r, 64);
            float iv1 = __shfl(inv, q1r, 64);
            size_t rowb = ((size_t)b * SEQ + t * 64 + fqh * 32);
            y[(rowb + q0r) * D_MODEL + h * 64 + dv * 32 + l31] = fb(o0 * iv0);
            y[(rowb + q1r) * D_MODEL + h * 64 + dv * 32 + l31] = fb(o1 * iv1);
        }
    }
}

extern "C" void kernel_launch(void* const* d_in, const int* in_sizes, int n_in,
                              void* d_out, int out_size, void* d_ws, size_t ws_size,
                              hipStream_t stream) {
    (void)in_sizes; (void)n_in; (void)out_size; (void)ws_size;
    const float* x     = (const float*)d_in[0];
    const float* W_in  = (const float*)d_in[1];
    const float* b_in  = (const float*)d_in[2];
    const float* W_out = (const float*)d_in[3];
    const float* b_out = (const float*)d_in[4];
    float* out = (float*)d_out;

    const int M = NB * SEQ;  // 8192
    char* p = (char*)d_ws;
    short* xbf   = (short*)p; p += (size_t)M * D_MODEL * 2;
    short* wtin  = (short*)p; p += (size_t)3 * D_MODEL * D_MODEL * 2;
    short* wtout = (short*)p; p += (size_t)D_MODEL * D_MODEL * 2;
    short* qimg  = (short*)p; p += (size_t)M * D_MODEL * 2;
    short* kimg  = (short*)p; p += (size_t)NB * NHEAD * 64 * 4096 * 2;
    short* vimg  = (short*)p; p += (size_t)NB * NHEAD * 64 * 4096 * 2;
    short* yw    = (short*)p;

    convert_bf16<<<dim3((unsigned)((size_t)M * D_MODEL / 8 / 256)), 256, 0, stream>>>(
        x, xbf, (size_t)M * D_MODEL);
    transpose_bf16<<<dim3(3 * D_MODEL / 32, D_MODEL / 32), dim3(32, 8), 0, stream>>>(
        W_in, wtin, D_MODEL, 3 * D_MODEL);
    transpose_bf16<<<dim3(D_MODEL / 32, D_MODEL / 32), dim3(32, 8), 0, stream>>>(
        W_out, wtout, D_MODEL, D_MODEL);
    gemm_qkv128<<<dim3(1152), 256, 0, stream>>>(xbf, wtin, b_in, qimg, kimg, vimg);
    attn_k<<<dim3(NB * NHEAD * 64), 256, 0, stream>>>(qimg, kimg, vimg, yw);
    gemm_out128<<<dim3(384), 256, 0, stream>>>(yw, wtout, b_out, out);
}

// Round 24
// 158.417 us; speedup vs baseline: 4.9286x; 1.0649x over previous
//
#include <hip/hip_runtime.h>
#include <hip/hip_bf16.h>

// B=2, S=4096, D=768, H=12, d_head=64.
// fused prep (x->bf16 + both W transposes, one launch) -> 128^2 m97 GEMM
// (BK=32, XCD-chunk-swizzled) writing Q/K/V fragment-order images ->
// flash attention (R16/R21: paired tiles, 4 waves stripe 65 positions,
// K via wave-private LDS buf, V direct-to-VGPR, vmcnt(8) top wait,
// fixed-max softmax, in-LDS dumps + single-barrier combine) -> 128^2 out GEMM.

#define D_MODEL 768
#define SEQ 4096
#define NB 2
#define NHEAD 12

typedef __attribute__((ext_vector_type(8))) short short8;
typedef __attribute__((ext_vector_type(4))) float floatx4;
typedef __attribute__((ext_vector_type(16))) float floatx16;

#define SM_C 0.18033688011112042f  /* 0.125 * log2(e) */

#if __has_builtin(__builtin_amdgcn_exp2f)
#define EXP2(x) __builtin_amdgcn_exp2f(x)
#else
#define EXP2(x) __expf((x) * 0.6931471805599453f)
#endif

__device__ inline short fb(float f) {
    union { __hip_bfloat16 h; short s; } cv;
    cv.h = __float2bfloat16(f);
    return cv.s;
}
__device__ inline unsigned pk2(float a, float b) {
    float2 f; f.x = a; f.y = b;
    union { __hip_bfloat162 h; unsigned u; } cv;
    cv.h = __float22bfloat162_rn(f);
    return cv.u;
}
__device__ inline void gload16(const void* g, void* l) {
    __builtin_amdgcn_global_load_lds(
        (const __attribute__((address_space(1))) unsigned int*)g,
        (__attribute__((address_space(3))) unsigned int*)l, 16, 0, 0);
}

// ---------------------------------------------------------------------------
// Fused prep: blocks [0,3072): x fp32->bf16 (8 elems/thread);
// [3072,4800): W_in transpose->bf16; [4800,5376): W_out transpose->bf16.
// ---------------------------------------------------------------------------
__global__ __launch_bounds__(256) void prep_fused(const float* __restrict__ x,
                                                  const float* __restrict__ W_in,
                                                  const float* __restrict__ W_out,
                                                  short* __restrict__ xbf,
                                                  short* __restrict__ wtin,
                                                  short* __restrict__ wtout) {
    const int bid = blockIdx.x, tid = threadIdx.x;
    if (bid < 3072) {                       // convert x
        size_t i = ((size_t)bid * 256 + tid) * 8;
        float4 f0 = *(const float4*)(x + i);
        float4 f1 = *(const float4*)(x + i + 4);
        uint4 u = {pk2(f0.x, f0.y), pk2(f0.z, f0.w), pk2(f1.x, f1.y), pk2(f1.z, f1.w)};
        *(uint4*)(xbf + i) = u;
        return;
    }
    // transpose W[K][N] -> Wt[N][K], 32x32 tiles
    __shared__ short t[32][33];
    const float* W; short* Wt; int N, n0, k0;
    if (bid < 4800) { W = W_in;  Wt = wtin;  N = 3 * D_MODEL;
                      int b2 = bid - 3072; n0 = (b2 % 72) * 32; k0 = (b2 / 72) * 32; }
    else            { W = W_out; Wt = wtout; N = D_MODEL;
                      int b2 = bid - 4800; n0 = (b2 % 24) * 32; k0 = (b2 / 24) * 32; }
    const int tx = tid & 31, ty = tid >> 5;
#pragma unroll
    for (int j = 0; j < 4; ++j)
        t[ty + j * 8][tx] = fb(W[(size_t)(k0 + ty + j * 8) * N + n0 + tx]);
    __syncthreads();
#pragma unroll
    for (int j = 0; j < 4; ++j)
        Wt[(size_t)(n0 + ty + j * 8) * D_MODEL + k0 + tx] = t[tx][ty + j * 8];
}

// ---------------------------------------------------------------------------
// QKV GEMM (m97 structure, BK=32, XCD-chunk swizzle). Fragment-order images.
// ---------------------------------------------------------------------------
__global__ __launch_bounds__(256) void gemm_qkv128(const short* __restrict__ A,
                                                   const short* __restrict__ Bt,
                                                   const float* __restrict__ bias,
                                                   short* __restrict__ qimg,
                                                   short* __restrict__ kimg,
                                                   short* __restrict__ vimg) {
    const int K = D_MODEL;
    __shared__ short As[128][32];
    __shared__ short Bs[128][32];
    const int tid = threadIdx.x, lane = tid & 63, w = tid >> 6;
    const int wr = w >> 1, wc = w & 1;
    const int lo = lane & 15, hi = lane >> 4;
    const int orig = (blockIdx.x & 7) * 144 + (blockIdx.x >> 3);
    const int m0 = (orig / 18) * 128, n0 = (orig % 18) * 128;
    const int lr = lane >> 2, lc = (lane & 3) * 8;

    floatx4 acc[4][4] = {};
    const short* Ag = A  + (size_t)(m0 + w * 16 + lr) * K + lc;
    const short* Bg = Bt + (size_t)(n0 + w * 16 + lr) * K + lc;

    for (int k0 = 0; k0 < K; k0 += 32) {
        __syncthreads();
        gload16(Ag + k0,                  &As[w * 16][0]);
        gload16(Ag + k0 + (size_t)64 * K, &As[64 + w * 16][0]);
        gload16(Bg + k0,                  &Bs[w * 16][0]);
        gload16(Bg + k0 + (size_t)64 * K, &Bs[64 + w * 16][0]);
        __syncthreads();
        short8 a[4], bf[4];
#pragma unroll
        for (int m = 0; m < 4; ++m) a[m] = *(const short8*)&As[wr * 64 + m * 16 + lo][hi * 8];
#pragma unroll
        for (int n = 0; n < 4; ++n) bf[n] = *(const short8*)&Bs[wc * 64 + n * 16 + lo][hi * 8];
#pragma unroll
        for (int m = 0; m < 4; ++m)
#pragma unroll
            for (int n = 0; n < 4; ++n)
                acc[m][n] = __builtin_amdgcn_mfma_f32_16x16x32_bf16(a[m], bf[n], acc[m][n], 0, 0, 0);
    }

#pragma unroll
    for (int m = 0; m < 4; ++m)
#pragma unroll
        for (int n = 0; n < 4; ++n) {
            int col  = n0 + wc * 64 + n * 16 + lo;
            int row0 = m0 + wr * 64 + m * 16 + hi * 4;
            float bv = bias[col];
            if (col < D_MODEL) {                    // Q (pre-scaled), per (b,h,tile)
                int hq = col >> 6, dh = col & 63;
                int kc = dh >> 4, dl = (dh >> 3) & 1, d7 = dh & 7;
#pragma unroll
                for (int r = 0; r < 4; ++r) {
                    int row = row0 + r;
                    int bb = row >> 12, s = row & 4095;
                    size_t off = (((((size_t)bb * NHEAD + hq) * 64 + (s >> 6)) * 8
                                  + ((s >> 5) & 1) * 4 + kc) * 512)
                               + ((s & 31) + dl * 32) * 8 + d7;
                    qimg[off] = fb((acc[m][n][r] + bv) * SM_C);
                }
            } else if (col < 2 * D_MODEL) {         // K fragment-order image
                int kc2 = col - D_MODEL;
                int hh = kc2 >> 6, dh = kc2 & 63;
                int kc = dh >> 4, dl = (dh >> 3) & 1, d7 = dh & 7;
#pragma unroll
                for (int r = 0; r < 4; ++r) {
                    int row = row0 + r;
                    int bb = row >> 12, s = row & 4095;
                    int kb = s >> 6, kr = s & 63;
                    size_t base = (((size_t)bb * NHEAD + hh) * 64 + kb) * 4096;
                    kimg[base + ((kr >> 5) * 4 + kc) * 512 + ((kr & 31) + dl * 32) * 8 + d7] =
                        fb(acc[m][n][r] + bv);
                }
            } else {                                // V fragment-order image
                int vcol = col - 2 * D_MODEL;
                int hh = vcol >> 6, dh = vcol & 63;
                int bb = row0 >> 12, s = row0 & 4095;
                int kb = s >> 6, kr = s & 63;
                size_t base = (((size_t)bb * NHEAD + hh) * 64 + kb) * 4096;
                size_t off = base + ((dh >> 5) * 4 + (kr >> 4)) * 512
                           + ((dh & 31) + ((kr >> 3) & 1) * 32) * 8 + (kr & 7);
                uint2 u = {pk2(acc[m][n][0] + bv, acc[m][n][1] + bv),
                           pk2(acc[m][n][2] + bv, acc[m][n][3] + bv)};
                *(uint2*)&vimg[off] = u;
            }
        }
}

// ---------------------------------------------------------------------------
__global__ __launch_bounds__(256) void gemm_out128(const short* __restrict__ A,
                                                   const short* __restrict__ Bt,
                                                   const float* __restrict__ bias,
                                                   float* __restrict__ C) {
    const int K = D_MODEL, N = D_MODEL;
    __shared__ short As[128][32];
    __shared__ short Bs[128][32];
    const int tid = threadIdx.x, lane = tid & 63, w = tid >> 6;
    const int wr = w >> 1, wc = w & 1;
    const int lo = lane & 15, hi = lane >> 4;
    const int orig = (blockIdx.x & 7) * 48 + (blockIdx.x >> 3);
    const int m0 = (orig / 6) * 128, n0 = (orig % 6) * 128;
    const int lr = lane >> 2, lc = (lane & 3) * 8;

    floatx4 acc[4][4] = {};
    const short* Ag = A  + (size_t)(m0 + w * 16 + lr) * K + lc;
    const short* Bg = Bt + (size_t)(n0 + w * 16 + lr) * K + lc;

    for (int k0 = 0; k0 < K; k0 += 32) {
        __syncthreads();
        gload16(Ag + k0,                  &As[w * 16][0]);
        gload16(Ag + k0 + (size_t)64 * K, &As[64 + w * 16][0]);
        gload16(Bg + k0,                  &Bs[w * 16][0]);
        gload16(Bg + k0 + (size_t)64 * K, &Bs[64 + w * 16][0]);
        __syncthreads();
        short8 a[4], bf[4];
#pragma unroll
        for (int m = 0; m < 4; ++m) a[m] = *(const short8*)&As[wr * 64 + m * 16 + lo][hi * 8];
#pragma unroll
        for (int n = 0; n < 4; ++n) bf[n] = *(const short8*)&Bs[wc * 64 + n * 16 + lo][hi * 8];
#pragma unroll
        for (int m = 0; m < 4; ++m)
#pragma unroll
            for (int n = 0; n < 4; ++n)
                acc[m][n] = __builtin_amdgcn_mfma_f32_16x16x32_bf16(a[m], bf[n], acc[m][n], 0, 0, 0);
    }

#pragma unroll
    for (int m = 0; m < 4; ++m)
#pragma unroll
        for (int n = 0; n < 4; ++n) {
            int col  = n0 + wc * 64 + n * 16 + lo;
            int row0 = m0 + wr * 64 + m * 16 + hi * 4;
            float bv = bias[col];
#pragma unroll
            for (int r = 0; r < 4; ++r)
                C[(size_t)(row0 + r) * N + col] = acc[m][n][r] + bv;
        }
}

// ---------------------------------------------------------------------------
// Flash attention (causal) — R16/R21. 768 blocks x 4 waves; block = tile pair
// {lo=ip, hi=63-ip}; 65-position sequence striped by wave. Each wave: 64 q,
// K via private 8KB LDS buf (no barriers), V direct to VGPR. Top wait
// vmcnt(8) (K-only drain). Fixed-max softmax; in-LDS dumps; 1-barrier combine.
// ---------------------------------------------------------------------------
__global__ __launch_bounds__(256, 2) void attn_k(const short* __restrict__ qimg,
                                                 const short* __restrict__ kimg,
                                                 const short* __restrict__ vimg,
                                                 short* __restrict__ y) {
    const int L = blockIdx.x;
    const int xcd = L & 7, slot = L >> 3;
    const int ghead = slot >> 5, ip = slot & 31;
    const int g = ghead * 8 + xcd;
    const int b = g / NHEAD, h = g % NHEAD;
    const int tid = threadIdx.x, lane = tid & 63, w = tid >> 6;
    const int l31 = lane & 31, hh = lane >> 5;

    __shared__ alignas(16) short KL[4][4096];   // per-wave K buf; reused for hi dumps
    __shared__ unsigned LOD[4][2048];           // lo partial dumps (bf16 pairs)
    __shared__ float LS[4][2][2][64];           // lsum dumps [w][lo/hi][qh][lane]

    const short* kbase = kimg + ((size_t)b * NHEAD + h) * 64 * 4096;
    const short* vbase = vimg + ((size_t)b * NHEAD + h) * 64 * 4096 + lane * 8;
    const short* qtbase = qimg + ((size_t)b * NHEAD + h) * 64 * 4096;
    short* Kbuf = &KL[w][0];

    const int nlo = ip + 1;
    const int npos = ((64 - w) >> 2) + 1;

    if (w >= nlo) {   // no lo work: zero my lo dump slot
#pragma unroll
        for (int r = 0; r < 32; ++r) LOD[w][r * 64 + lane] = 0u;
        LS[w][0][0][lane] = 0.0f;
        LS[w][0][1][lane] = 0.0f;
    }

    floatx16 Oa = {}, Ob = {}, Oc = {}, Od = {};  // [qh0dv0][qh0dv1][qh1dv0][qh1dv1]
    float ls0 = 0.0f, ls1 = 0.0f;
    short8 qf0[4], qf1[4], vf[8];

    int curtile = (w < nlo) ? ip : (63 - ip);
    {
        const short* qr = qtbase + (size_t)curtile * 4096 + lane * 8;
#pragma unroll
        for (int kc = 0; kc < 4; ++kc) {
            qf0[kc] = *(const short8*)(qr + kc * 512);
            qf1[kc] = *(const short8*)(qr + (4 + kc) * 512);
        }
    }
    {   // prologue: K(pos0) -> LDS (first: oldest), V(pos0) -> regs
        int kb0 = (w < nlo) ? w : (w - nlo);
        const short* ks = kbase + (size_t)kb0 * 4096 + lane * 8;
#pragma unroll
        for (int c = 0; c < 8; ++c) gload16(ks + c * 512, Kbuf + c * 512);
        const short* vs = vbase + (size_t)kb0 * 4096;
#pragma unroll
        for (int i = 0; i < 8; ++i) vf[i] = *(const short8*)(vs + i * 512);
    }

    for (int it = 0; it < npos; ++it) {
        const int s = w + 4 * it;
        const int tile = (s < nlo) ? ip : (63 - ip);
        const int kblk = (s < nlo) ? s : (s - nlo);

        if (tile != curtile) {   // lo -> hi transition (wave-uniform, once)
#pragma unroll
            for (int rp = 0; rp < 8; ++rp) {
                LOD[w][(0 * 8 + rp) * 64 + lane] = pk2(Oa[2 * rp], Oa[2 * rp + 1]);
                LOD[w][(1 * 8 + rp) * 64 + lane] = pk2(Ob[2 * rp], Ob[2 * rp + 1]);
                LOD[w][(2 * 8 + rp) * 64 + lane] = pk2(Oc[2 * rp], Oc[2 * rp + 1]);
                LOD[w][(3 * 8 + rp) * 64 + lane] = pk2(Od[2 * rp], Od[2 * rp + 1]);
            }
            LS[w][0][0][lane] = ls0;
            LS[w][0][1][lane] = ls1;
#pragma unroll
            for (int r = 0; r < 16; ++r) { Oa[r] = 0.0f; Ob[r] = 0.0f; Oc[r] = 0.0f; Od[r] = 0.0f; }
            ls0 = ls1 = 0.0f;
            const short* qr = qtbase + (size_t)tile * 4096 + lane * 8;
#pragma unroll
            for (int kc = 0; kc < 4; ++kc) {
                qf0[kc] = *(const short8*)(qr + kc * 512);
                qf1[kc] = *(const short8*)(qr + (4 + kc) * 512);
            }
            curtile = tile;
        }

        // counted wait: K(it) landed in Kbuf; V(it) (8 loads) stays in flight.
        asm volatile("s_waitcnt vmcnt(8)" ::: "memory");
        __builtin_amdgcn_sched_barrier(0);

        // ---- QK (both 32-key halves) from private K buffer
        floatx16 S00 = {}, S10 = {}, S01 = {}, S11 = {};   // S[qh][kb2]
        __builtin_amdgcn_s_setprio(1);
#pragma unroll
        for (int kc = 0; kc < 4; ++kc) {
            short8 kf = *(const short8*)&Kbuf[kc * 512 + lane * 8];
            S00 = __builtin_amdgcn_mfma_f32_32x32x16_bf16(kf, qf0[kc], S00, 0, 0, 0);
            S10 = __builtin_amdgcn_mfma_f32_32x32x16_bf16(kf, qf1[kc], S10, 0, 0, 0);
        }
#pragma unroll
        for (int kc = 0; kc < 4; ++kc) {
            short8 kf = *(const short8*)&Kbuf[(4 + kc) * 512 + lane * 8];
            S01 = __builtin_amdgcn_mfma_f32_32x32x16_bf16(kf, qf0[kc], S01, 0, 0, 0);
            S11 = __builtin_amdgcn_mfma_f32_32x32x16_bf16(kf, qf1[kc], S11, 0, 0, 0);
        }
        __builtin_amdgcn_s_setprio(0);
        __builtin_amdgcn_sched_barrier(0);

        // ---- issue K(next) into the (now fully consumed) private buffer
        if (it + 1 < npos) {
            int sn = s + 4;
            int nk = (sn < nlo) ? sn : (sn - nlo);
            const short* ks = kbase + (size_t)nk * 4096 + lane * 8;
#pragma unroll
            for (int c = 0; c < 8; ++c) gload16(ks + c * 512, Kbuf + c * 512);
        }
        __builtin_amdgcn_sched_barrier(0);

        // ---- mask (diagonal block only)
        if (kblk == tile) {
            const int qg0 = tile * 64 + l31, qg1 = qg0 + 32;
#pragma unroll
            for (int kb2 = 0; kb2 < 2; ++kb2) {
                int kb_base = kblk * 64 + kb2 * 32 + 4 * hh;
#pragma unroll
                for (int r = 0; r < 16; ++r) {
                    int kgl = kb_base + (r & 3) + 8 * (r >> 2);
                    if (kb2 == 0) {
                        if (kgl > qg0) S00[r] = -1e30f;
                        if (kgl > qg1) S10[r] = -1e30f;
                    } else {
                        if (kgl > qg0) S01[r] = -1e30f;
                        if (kgl > qg1) S11[r] = -1e30f;
                    }
                }
            }
        }

        // ---- softmax + pack + PV, per (qh, kb2); compiler waits vf before PV
#pragma unroll
        for (int kb2 = 0; kb2 < 2; ++kb2) {
            // qh = 0
            {
                floatx16& S = kb2 ? S01 : S00;
                unsigned wA[4], wB[4];
#pragma unroll
                for (int g4 = 0; g4 < 4; ++g4) {
                    float p0 = EXP2(S[4 * g4 + 0]), p1 = EXP2(S[4 * g4 + 1]);
                    float p2 = EXP2(S[4 * g4 + 2]), p3 = EXP2(S[4 * g4 + 3]);
                    ls0 += (p0 + p1) + (p2 + p3);
                    wA[g4] = pk2(p0, p1);
                    wB[g4] = pk2(p2, p3);
                }
#pragma unroll
                for (int c16 = 0; c16 < 2; ++c16) {
                    unsigned xa = wA[2 * c16], ya = wA[2 * c16 + 1];
                    unsigned xb = wB[2 * c16], yb = wB[2 * c16 + 1];
                    asm("v_permlane32_swap_b32 %0, %1" : "+v"(xa), "+v"(ya));
                    asm("v_permlane32_swap_b32 %0, %1" : "+v"(xb), "+v"(yb));
                    union { unsigned u[4]; short8 s8; } pa;
                    pa.u[0] = xa; pa.u[1] = xb; pa.u[2] = ya; pa.u[3] = yb;
                    const int kcg = kb2 * 2 + c16;
                    __builtin_amdgcn_s_setprio(1);
                    Oa = __builtin_amdgcn_mfma_f32_32x32x16_bf16(pa.s8, vf[kcg],     Oa, 0, 0, 0);
                    Ob = __builtin_amdgcn_mfma_f32_32x32x16_bf16(pa.s8, vf[4 + kcg], Ob, 0, 0, 0);
                    __builtin_amdgcn_s_setprio(0);
                }
            }
            // qh = 1
            {
                floatx16& S = kb2 ? S11 : S10;
                unsigned wA[4], wB[4];
#pragma unroll
                for (int g4 = 0; g4 < 4; ++g4) {
                    float p0 = EXP2(S[4 * g4 + 0]), p1 = EXP2(S[4 * g4 + 1]);
                    float p2 = EXP2(S[4 * g4 + 2]), p3 = EXP2(S[4 * g4 + 3]);
                    ls1 += (p0 + p1) + (p2 + p3);
                    wA[g4] = pk2(p0, p1);
                    wB[g4] = pk2(p2, p3);
                }
#pragma unroll
                for (int c16 = 0; c16 < 2; ++c16) {
                    unsigned xa = wA[2 * c16], ya = wA[2 * c16 + 1];
                    unsigned xb = wB[2 * c16], yb = wB[2 * c16 + 1];
                    asm("v_permlane32_swap_b32 %0, %1" : "+v"(xa), "+v"(ya));
                    asm("v_permlane32_swap_b32 %0, %1" : "+v"(xb), "+v"(yb));
                    union { unsigned u[4]; short8 s8; } pa;
                    pa.u[0] = xa; pa.u[1] = xb; pa.u[2] = ya; pa.u[3] = yb;
                    const int kcg = kb2 * 2 + c16;
                    __builtin_amdgcn_s_setprio(1);
                    Oc = __builtin_amdgcn_mfma_f32_32x32x16_bf16(pa.s8, vf[kcg],     Oc, 0, 0, 0);
                    Od = __builtin_amdgcn_mfma_f32_32x32x16_bf16(pa.s8, vf[4 + kcg], Od, 0, 0, 0);
                    __builtin_amdgcn_s_setprio(0);
                }
            }
        }
        __builtin_amdgcn_sched_barrier(0);

        // ---- issue V(next)
        if (it + 1 < npos) {
            int sn = s + 4;
            int nk = (sn < nlo) ? sn : (sn - nlo);
            const short* vs = vbase + (size_t)nk * 4096;
#pragma unroll
            for (int i = 0; i < 8; ++i) vf[i] = *(const short8*)(vs + i * 512);
        }
        __builtin_amdgcn_sched_barrier(0);
    }

    // ---- dump hi partials into my (dead) K buffer
    {
        unsigned* hslot = (unsigned*)&KL[w][0];
#pragma unroll
        for (int rp = 0; rp < 8; ++rp) {
            hslot[(0 * 8 + rp) * 64 + lane] = pk2(Oa[2 * rp], Oa[2 * rp + 1]);
            hslot[(1 * 8 + rp) * 64 + lane] = pk2(Ob[2 * rp], Ob[2 * rp + 1]);
            hslot[(2 * 8 + rp) * 64 + lane] = pk2(Oc[2 * rp], Oc[2 * rp + 1]);
            hslot[(3 * 8 + rp) * 64 + lane] = pk2(Od[2 * rp], Od[2 * rp + 1]);
        }
        LS[w][1][0][lane] = ls0;
        LS[w][1][1][lane] = ls1;
    }
    __syncthreads();

    // ---- combine: wave w finalizes (tile = w>>1 ? hi : lo, qh = w&1)
    {
        const int tsel = w >> 1;
        const int fqh = w & 1;
        const int ftile = tsel ? (63 - ip) : ip;

        float lt = 0.0f;
#pragma unroll
        for (int ww = 0; ww < 4; ++ww)
            lt += LS[ww][tsel][fqh][l31] + LS[ww][tsel][fqh][l31 + 32];
        float inv = 1.0f / lt;

#pragma unroll
        for (int dv = 0; dv < 2; ++dv) {
#pragma unroll
            for (int rp = 0; rp < 8; ++rp) {
                float o0 = 0.0f, o1 = 0.0f;
#pragma unroll
                for (int ww = 0; ww < 4; ++ww) {
                    unsigned u = tsel
                        ? ((const unsigned*)&KL[ww][0])[((fqh * 2 + dv) * 8 + rp) * 64 + lane]
                        : LOD[ww][((fqh * 2 + dv) * 8 + rp) * 64 + lane];
                    o0 += __builtin_bit_cast(float, u << 16);
                    o1 += __builtin_bit_cast(float, u & 0xffff0000u);
                }
                int r0 = 2 * rp, r1 = 2 * rp + 1;
                int q0r = (r0 & 3) + 8 * (r0 >> 2) + 4 * hh;
                int q1r = (r1 & 3) + 8 * (r1 >> 2) + 4 * hh;
                float iv0 = __shfl(inv, q0r, 64);
                float iv1 = __shfl(inv, q1r, 64);
                size_t rowb = ((size_t)b * SEQ + ftile * 64 + fqh * 32);
                y[(rowb + q0r) * D_MODEL + h * 64 + dv * 32 + l31] = fb(o0 * iv0);
                y[(rowb + q1r) * D_MODEL + h * 64 + dv * 32 + l31] = fb(o1 * iv1);
            }
        }
    }
}

extern "C" void kernel_launch(void* const* d_in, const int* in_sizes, int n_in,
                              void* d_out, int out_size, void* d_ws, size_t ws_size,
                              hipStream_t stream) {
    (void)in_sizes; (void)n_in; (void)out_size; (void)ws_size;
    const float* x     = (const float*)d_in[0];
    const float* W_in  = (const float*)d_in[1];
    const float* b_in  = (const float*)d_in[2];
    const float* W_out = (const float*)d_in[3];
    const float* b_out = (const float*)d_in[4];
    float* out = (float*)d_out;

    const int M = NB * SEQ;  // 8192
    char* p = (char*)d_ws;
    short* xbf   = (short*)p; p += (size_t)M * D_MODEL * 2;
    short* wtin  = (short*)p; p += (size_t)3 * D_MODEL * D_MODEL * 2;
    short* wtout = (short*)p; p += (size_t)D_MODEL * D_MODEL * 2;
    short* qimg  = (short*)p; p += (size_t)M * D_MODEL * 2;
    short* kimg  = (short*)p; p += (size_t)NB * NHEAD * 64 * 4096 * 2;
    short* vimg  = (short*)p; p += (size_t)NB * NHEAD * 64 * 4096 * 2;
    short* yw    = (short*)p;

    prep_fused<<<dim3(5376), 256, 0, stream>>>(x, W_in, W_out, xbf, wtin, wtout);
    gemm_qkv128<<<dim3(1152), 256, 0, stream>>>(xbf, wtin, b_in, qimg, kimg, vimg);
    attn_k<<<dim3(NB * NHEAD * 32), 256, 0, stream>>>(qimg, kimg, vimg, yw);
    gemm_out128<<<dim3(384), 256, 0, stream>>>(yw, wtout, b_out, out);
}